// Round 1
// baseline (1418.769 us; speedup 1.0000x reference)
//
#include <hip/hip_runtime.h>
#include <math.h>

#define N 3072
#define FEAT 128
#define NE 24576
#define PROP_ITERS 14

__device__ __forceinline__ int ldl(const int* p) {
    return __hip_atomic_load(p, __ATOMIC_RELAXED, __HIP_MEMORY_SCOPE_AGENT);
}

// a[i] = x[i] . w[0:128],  c[i] = x[i] . w[128:256]
__global__ void k_dots(const float* __restrict__ x, const float* __restrict__ w,
                       float* __restrict__ a, float* __restrict__ c) {
    int i = blockIdx.x;          // node
    int l = threadIdx.x;         // lane 0..63
    const float* xi = x + i * FEAT;
    float pa = xi[l] * w[l] + xi[l + 64] * w[l + 64];
    float pc = xi[l] * w[FEAT + l] + xi[l + 64] * w[FEAT + l + 64];
    for (int off = 32; off; off >>= 1) {
        pa += __shfl_down(pa, off);
        pc += __shfl_down(pc, off);
    }
    if (l == 0) { a[i] = pa; c[i] = pc; }
}

__global__ void k_init_labels(int* labels) {
    int i = blockIdx.x * blockDim.x + threadIdx.x;
    if (i < N) labels[i] = i;
}

// mark nodes touched by any contraction edge (row OR column of A_c)
__global__ void k_mark(const int* __restrict__ ei, const float* __restrict__ a,
                       const float* __restrict__ c, const float* __restrict__ bb,
                       int* __restrict__ notsingle) {
    int t = blockIdx.x * blockDim.x + threadIdx.x;
    if (t >= NE) return;
    int u = ei[t], v = ei[NE + t];
    if (u == v) return;
    float b = bb[0];
    if (a[u] + c[v] + b > 0.f || a[v] + c[u] + b > 0.f) {
        notsingle[u] = 1;
        notsingle[v] = 1;
    }
}

// one round: edge atomicMin propagation + per-node path compression
__global__ void k_prop(const int* __restrict__ ei, const float* __restrict__ a,
                       const float* __restrict__ c, const float* __restrict__ bb,
                       int* labels) {
    int t = blockIdx.x * blockDim.x + threadIdx.x;
    if (t < NE) {
        int u = ei[t], v = ei[NE + t];
        if (u != v) {
            float b = bb[0];
            if (a[u] + c[v] + b > 0.f) atomicMin(&labels[u], ldl(&labels[v]));
            if (a[v] + c[u] + b > 0.f) atomicMin(&labels[v], ldl(&labels[u]));
        }
    } else {
        int i = t - NE;
        if (i < N) {
            int m = ldl(&labels[i]);
            for (;;) {
                int mm = ldl(&labels[m]);
                if (mm >= m) break;
                m = mm;
            }
            atomicMin(&labels[i], m);
        }
    }
}

// rank roots (cumsum of labels[i]==i minus 1), then cluster[i] = rank[labels[i]]
__global__ void k_rank(const int* __restrict__ labels, int* __restrict__ rank,
                       int* __restrict__ cluster) {
    __shared__ int ssum[1024];
    int t = threadIdx.x;
    int i0 = 3 * t;
    int r0 = (labels[i0] == i0);
    int r1 = (labels[i0 + 1] == i0 + 1);
    int r2 = (labels[i0 + 2] == i0 + 2);
    int s = r0 + r1 + r2;
    ssum[t] = s;
    __syncthreads();
    for (int off = 1; off < 1024; off <<= 1) {
        int val = (t >= off) ? ssum[t - off] : 0;
        __syncthreads();
        ssum[t] += val;
        __syncthreads();
    }
    int run = ssum[t] - s;   // exclusive prefix
    run += r0; rank[i0]     = run - 1;
    run += r1; rank[i0 + 1] = run - 1;
    run += r2; rank[i0 + 2] = run - 1;
    __syncthreads();
    for (int j = t; j < N; j += 1024) cluster[j] = rank[labels[j]];
}

// one wave per original edge; dedup ordered pairs via bitmask; accumulate
// X_new[cluster[q]] += e(p,q)*x[p]  and  A_new[cluster[p],cluster[q]] += 1
__global__ void k_accum(const int* __restrict__ ei, const float* __restrict__ x,
                        const float* __restrict__ a, const float* __restrict__ c,
                        const float* __restrict__ bb, const int* __restrict__ cluster,
                        unsigned* __restrict__ mask, float* __restrict__ Xnew,
                        float* __restrict__ Anew) {
    int wid = (blockIdx.x * blockDim.x + threadIdx.x) >> 6;
    int lane = threadIdx.x & 63;
    if (wid >= NE) return;
    int u = ei[wid], v = ei[NE + wid];
    if (u == v) return;
    float b = bb[0];
    for (int dir = 0; dir < 2; ++dir) {
        int p = dir ? v : u;
        int q = dir ? u : v;
        int own = 0;
        if (lane == 0) {
            unsigned pos = (unsigned)p * N + (unsigned)q;
            unsigned bit = 1u << (pos & 31u);
            unsigned old = atomicOr(&mask[pos >> 5], bit);
            own = !(old & bit);
        }
        own = __shfl(own, 0);
        if (!own) continue;
        float e = tanhf(a[p] + c[q] + b);
        int cq = cluster[q];
        if (lane == 0) atomicAdd(&Anew[cluster[p] * N + cq], 1.0f);
        const float* xp = x + p * FEAT;
        float* Xq = Xnew + cq * FEAT;
        atomicAdd(&Xq[lane], e * xp[lane]);
        atomicAdd(&Xq[lane + 64], e * xp[lane + 64]);
    }
}

// isolated-under-contraction nodes contribute x[j] to their own cluster row
__global__ void k_single(const float* __restrict__ x, const int* __restrict__ notsingle,
                         const int* __restrict__ cluster, float* __restrict__ Xnew) {
    int wid = (blockIdx.x * blockDim.x + threadIdx.x) >> 6;
    int lane = threadIdx.x & 63;
    if (wid >= N) return;
    if (notsingle[wid]) return;
    int cq = cluster[wid];
    const float* xp = x + wid * FEAT;
    float* Xq = Xnew + cq * FEAT;
    atomicAdd(&Xq[lane], xp[lane]);
    atomicAdd(&Xq[lane + 64], xp[lane + 64]);
}

// zero A_new diagonal, write cluster (as float) and new_batch (zeros already)
__global__ void k_final(const int* __restrict__ cluster, float* __restrict__ Anew,
                        float* __restrict__ out_cluster) {
    int i = blockIdx.x * blockDim.x + threadIdx.x;
    if (i >= N) return;
    Anew[i * N + i] = 0.0f;
    out_cluster[i] = (float)cluster[i];
}

extern "C" void kernel_launch(void* const* d_in, const int* in_sizes, int n_in,
                              void* d_out, int out_size, void* d_ws, size_t ws_size,
                              hipStream_t stream) {
    const float* x  = (const float*)d_in[0];
    const int*   ei = (const int*)d_in[1];
    // d_in[2] = batch (all zeros, unused)
    const float* w  = (const float*)d_in[3];
    const float* bb = (const float*)d_in[4];

    // workspace layout
    char* ws = (char*)d_ws;
    float* a        = (float*)(ws + 0 * N * 4);
    float* c        = (float*)(ws + 1 * N * 4);
    int*   labels   = (int*)  (ws + 2 * N * 4);
    int*   notsing  = (int*)  (ws + 3 * N * 4);
    int*   rank     = (int*)  (ws + 4 * N * 4);
    int*   cluster  = (int*)  (ws + 5 * N * 4);
    unsigned* mask  = (unsigned*)(ws + 6 * N * 4);
    size_t mask_bytes = (size_t)N * N / 8;   // 1,179,648 bytes

    // output layout (all float32)
    float* Xnew        = (float*)d_out;                         // N*FEAT
    float* Anew        = Xnew + (size_t)N * FEAT;               // N*N
    float* out_cluster = Anew + (size_t)N * N + N;              // after new_batch

    hipMemsetAsync(d_out, 0, (size_t)out_size * 4, stream);
    hipMemsetAsync(mask, 0, mask_bytes, stream);
    hipMemsetAsync(notsing, 0, N * 4, stream);

    k_dots<<<N, 64, 0, stream>>>(x, w, a, c);
    k_init_labels<<<(N + 255) / 256, 256, 0, stream>>>(labels);
    k_mark<<<(NE + 255) / 256, 256, 0, stream>>>(ei, a, c, bb, notsing);

    int prop_threads = NE + N;
    for (int it = 0; it < PROP_ITERS; ++it)
        k_prop<<<(prop_threads + 255) / 256, 256, 0, stream>>>(ei, a, c, bb, labels);

    k_rank<<<1, 1024, 0, stream>>>(labels, rank, cluster);

    k_accum<<<(NE * 64) / 256, 256, 0, stream>>>(ei, x, a, c, bb, cluster, mask, Xnew, Anew);
    k_single<<<(N * 64) / 256, 256, 0, stream>>>(x, notsing, cluster, Xnew);
    k_final<<<(N + 255) / 256, 256, 0, stream>>>(cluster, Anew, out_cluster);
}

// Round 2
// 274.579 us; speedup vs baseline: 5.1671x; 5.1671x over previous
//
#include <hip/hip_runtime.h>
#include <math.h>

#define N 3072
#define FEAT 128
#define NE 24576
#define NP (2 * NE)          // directed pair slots
#define PROP_ITERS 14

__device__ __forceinline__ int ldl(const int* p) {
    return __hip_atomic_load(p, __ATOMIC_RELAXED, __HIP_MEMORY_SCOPE_AGENT);
}

// Wave-aggregated atomic add: group lanes by key, one atomicAdd per distinct
// key per wave. All 64 lanes must reach this call (use `valid`, not early-return).
__device__ __forceinline__ void wave_agg_add(bool valid, int key, float val,
                                             float* base, int stride, int off) {
    int lane = threadIdx.x & 63;
    unsigned long long active = __ballot(valid ? 1 : 0);
    while (active) {
        int leader = __ffsll(active) - 1;
        int lkey = __shfl(key, leader);
        bool mine = valid && (key == lkey);
        unsigned long long grp = __ballot(mine ? 1 : 0);
        float v = mine ? val : 0.0f;
        #pragma unroll
        for (int o = 32; o; o >>= 1) v += __shfl_xor(v, o);
        if (lane == leader)
            atomicAdd(&base[(size_t)lkey * stride + off], v);
        active &= ~grp;
    }
}

// a[i] = x[i] . w[0:128],  c[i] = x[i] . w[128:256]
__global__ void k_dots(const float* __restrict__ x, const float* __restrict__ w,
                       float* __restrict__ a, float* __restrict__ c) {
    int i = blockIdx.x;
    int l = threadIdx.x;
    const float* xi = x + i * FEAT;
    float pa = xi[l] * w[l] + xi[l + 64] * w[l + 64];
    float pc = xi[l] * w[FEAT + l] + xi[l + 64] * w[FEAT + l + 64];
    for (int off = 32; off; off >>= 1) {
        pa += __shfl_down(pa, off);
        pc += __shfl_down(pc, off);
    }
    if (l == 0) { a[i] = pa; c[i] = pc; }
}

__global__ void k_init_labels(int* labels) {
    int i = blockIdx.x * blockDim.x + threadIdx.x;
    if (i < N) labels[i] = i;
}

// mark nodes touched by any contraction edge (row OR column of A_c)
__global__ void k_mark(const int* __restrict__ ei, const float* __restrict__ a,
                       const float* __restrict__ c, const float* __restrict__ bb,
                       int* __restrict__ notsingle) {
    int t = blockIdx.x * blockDim.x + threadIdx.x;
    if (t >= NE) return;
    int u = ei[t], v = ei[NE + t];
    if (u == v) return;
    float b = bb[0];
    if (a[u] + c[v] + b > 0.f || a[v] + c[u] + b > 0.f) {
        notsingle[u] = 1;
        notsingle[v] = 1;
    }
}

// one round: edge atomicMin propagation + per-node path compression
__global__ void k_prop(const int* __restrict__ ei, const float* __restrict__ a,
                       const float* __restrict__ c, const float* __restrict__ bb,
                       int* labels) {
    int t = blockIdx.x * blockDim.x + threadIdx.x;
    if (t < NE) {
        int u = ei[t], v = ei[NE + t];
        if (u != v) {
            float b = bb[0];
            if (a[u] + c[v] + b > 0.f) atomicMin(&labels[u], ldl(&labels[v]));
            if (a[v] + c[u] + b > 0.f) atomicMin(&labels[v], ldl(&labels[u]));
        }
    } else {
        int i = t - NE;
        if (i < N) {
            int m = ldl(&labels[i]);
            for (;;) {
                int mm = ldl(&labels[m]);
                if (mm >= m) break;
                m = mm;
            }
            atomicMin(&labels[i], m);
        }
    }
}

// rank roots (cumsum of labels[i]==i minus 1), then cluster[i] = rank[labels[i]]
__global__ void k_rank(const int* __restrict__ labels, int* __restrict__ rank,
                       int* __restrict__ cluster) {
    __shared__ int ssum[1024];
    int t = threadIdx.x;
    int i0 = 3 * t;
    int r0 = (labels[i0] == i0);
    int r1 = (labels[i0 + 1] == i0 + 1);
    int r2 = (labels[i0 + 2] == i0 + 2);
    int s = r0 + r1 + r2;
    ssum[t] = s;
    __syncthreads();
    for (int off = 1; off < 1024; off <<= 1) {
        int val = (t >= off) ? ssum[t - off] : 0;
        __syncthreads();
        ssum[t] += val;
        __syncthreads();
    }
    int run = ssum[t] - s;
    run += r0; rank[i0]     = run - 1;
    run += r1; rank[i0 + 1] = run - 1;
    run += r2; rank[i0 + 2] = run - 1;
    __syncthreads();
    for (int j = t; j < N; j += 1024) cluster[j] = rank[labels[j]];
}

// One lane per directed pair slot: dedup via bitmask, store ownership + score,
// wave-aggregated count into A_new[cluster[p]*N + cluster[q]].
__global__ void k_pairs(const int* __restrict__ ei, const float* __restrict__ a,
                        const float* __restrict__ c, const float* __restrict__ bb,
                        const int* __restrict__ cluster, unsigned* __restrict__ mask,
                        unsigned char* __restrict__ own, float* __restrict__ ev,
                        float* __restrict__ Anew) {
    int t = blockIdx.x * blockDim.x + threadIdx.x;   // exactly NP threads
    int dir = (t >= NE) ? 1 : 0;
    int idx = dir ? t - NE : t;
    int u = ei[idx], v = ei[NE + idx];
    int p = dir ? v : u;
    int q = dir ? u : v;
    int o = 0;
    if (p != q) {
        unsigned pos = (unsigned)p * N + (unsigned)q;
        unsigned bit = 1u << (pos & 31u);
        unsigned old = atomicOr(&mask[pos >> 5], bit);
        o = !(old & bit);
    }
    own[t] = (unsigned char)o;
    float e = 0.f;
    int key = 0;
    if (o) {
        e = tanhf(a[p] + c[q] + bb[0]);
        key = cluster[p] * N + cluster[q];
    }
    ev[t] = e;
    wave_agg_add(o != 0, key, 1.0f, Anew, 1, 0);
}

// One wave per owned pair slot: y[q] += e(p,q) * x[p]  (atomics spread over N rows)
__global__ void k_scatter(const int* __restrict__ ei, const float* __restrict__ x,
                          const unsigned char* __restrict__ own,
                          const float* __restrict__ ev, float* __restrict__ y) {
    int wid = (blockIdx.x * blockDim.x + threadIdx.x) >> 6;
    int lane = threadIdx.x & 63;
    if (wid >= NP) return;
    if (!own[wid]) return;
    int dir = (wid >= NE) ? 1 : 0;
    int idx = dir ? wid - NE : wid;
    int u = ei[idx], v = ei[NE + idx];
    int p = dir ? v : u;
    int q = dir ? u : v;
    float e = ev[wid];
    const float* xp = x + p * FEAT;
    float* yq = y + q * FEAT;
    atomicAdd(&yq[lane], e * xp[lane]);
    atomicAdd(&yq[lane + 64], e * xp[lane + 64]);
}

// isolated-under-contraction nodes: y[q] += x[q]
__global__ void k_single(const float* __restrict__ x, const int* __restrict__ notsingle,
                         const int* __restrict__ cluster, float* __restrict__ y) {
    int wid = (blockIdx.x * blockDim.x + threadIdx.x) >> 6;
    int lane = threadIdx.x & 63;
    if (wid >= N) return;
    if (notsingle[wid]) return;
    const float* xp = x + wid * FEAT;
    float* yq = y + wid * FEAT;
    atomicAdd(&yq[lane], xp[lane]);
    atomicAdd(&yq[lane + 64], xp[lane + 64]);
}

// X_new[cluster[q]][f] += y[q][f], wave-aggregated by cluster key.
// Wave layout: f = wid & 127, node chunk = wid >> 7, q = chunk*64 + lane.
__global__ void k_reduce(const float* __restrict__ y, const int* __restrict__ cluster,
                         float* __restrict__ Xnew) {
    int wid = (blockIdx.x * blockDim.x + threadIdx.x) >> 6;  // 0..6143
    int lane = threadIdx.x & 63;
    int f = wid & (FEAT - 1);
    int chunk = wid >> 7;
    int q = chunk * 64 + lane;
    float val = y[q * FEAT + f];
    int key = cluster[q];
    wave_agg_add(true, key, val, Xnew, FEAT, f);
}

// zero A_new diagonal, write cluster (as float); new_batch already zero
__global__ void k_final(const int* __restrict__ cluster, float* __restrict__ Anew,
                        float* __restrict__ out_cluster) {
    int i = blockIdx.x * blockDim.x + threadIdx.x;
    if (i >= N) return;
    Anew[i * N + i] = 0.0f;
    out_cluster[i] = (float)cluster[i];
}

extern "C" void kernel_launch(void* const* d_in, const int* in_sizes, int n_in,
                              void* d_out, int out_size, void* d_ws, size_t ws_size,
                              hipStream_t stream) {
    const float* x  = (const float*)d_in[0];
    const int*   ei = (const int*)d_in[1];
    const float* w  = (const float*)d_in[3];
    const float* bb = (const float*)d_in[4];

    // workspace layout
    char* ws = (char*)d_ws;
    float* a        = (float*)(ws + 0 * N * 4);
    float* c        = (float*)(ws + 1 * N * 4);
    int*   labels   = (int*)  (ws + 2 * N * 4);
    int*   notsing  = (int*)  (ws + 3 * N * 4);
    int*   rank     = (int*)  (ws + 4 * N * 4);
    int*   cluster  = (int*)  (ws + 5 * N * 4);
    size_t off = 6 * N * 4;
    unsigned* mask  = (unsigned*)(ws + off);        off += (size_t)N * N / 8;   // 1.18 MB
    unsigned char* own = (unsigned char*)(ws + off); off += NP;                 // 48 KB
    float* ev       = (float*)(ws + off);           off += (size_t)NP * 4;      // 192 KB
    float* y        = (float*)(ws + off);           off += (size_t)N * FEAT * 4;// 1.5 MB

    // output layout (all float32)
    float* Xnew        = (float*)d_out;                 // N*FEAT
    float* Anew        = Xnew + (size_t)N * FEAT;       // N*N
    float* out_cluster = Anew + (size_t)N * N + N;      // after new_batch

    hipMemsetAsync(d_out, 0, (size_t)out_size * 4, stream);
    hipMemsetAsync(mask, 0, (size_t)N * N / 8, stream);
    hipMemsetAsync(notsing, 0, N * 4, stream);
    hipMemsetAsync(y, 0, (size_t)N * FEAT * 4, stream);

    k_dots<<<N, 64, 0, stream>>>(x, w, a, c);
    k_init_labels<<<(N + 255) / 256, 256, 0, stream>>>(labels);
    k_mark<<<(NE + 255) / 256, 256, 0, stream>>>(ei, a, c, bb, notsing);

    int prop_threads = NE + N;
    for (int it = 0; it < PROP_ITERS; ++it)
        k_prop<<<(prop_threads + 255) / 256, 256, 0, stream>>>(ei, a, c, bb, labels);

    k_rank<<<1, 1024, 0, stream>>>(labels, rank, cluster);

    k_pairs<<<NP / 256, 256, 0, stream>>>(ei, a, c, bb, cluster, mask, own, ev, Anew);
    k_scatter<<<(NP * 64) / 256, 256, 0, stream>>>(ei, x, own, ev, y);
    k_single<<<(N * 64) / 256, 256, 0, stream>>>(x, notsing, cluster, y);
    k_reduce<<<(128 * 48 * 64) / 256, 256, 0, stream>>>(y, cluster, Xnew);
    k_final<<<(N + 255) / 256, 256, 0, stream>>>(cluster, Anew, out_cluster);
}

// Round 3
// 186.061 us; speedup vs baseline: 7.6253x; 1.4757x over previous
//
#include <hip/hip_runtime.h>
#include <math.h>

#define N 3072
#define FEAT 128
#define NE 24576
#define NP (2 * NE)          // directed pair slots
#define ZB 675               // zero-blocks: 675 * 4096 B = 2,764,800 B exactly

// Wave-aggregated atomic add: group lanes by key, one atomicAdd per distinct
// key per wave. All 64 lanes must reach this call (use `valid`, not early-return).
__device__ __forceinline__ void wave_agg_add(bool valid, int key, float val,
                                             float* base, int stride, int off) {
    int lane = threadIdx.x & 63;
    unsigned long long active = __ballot(valid ? 1 : 0);
    while (active) {
        int leader = __ffsll(active) - 1;
        int lkey = __shfl(key, leader);
        bool mine = valid && (key == lkey);
        unsigned long long grp = __ballot(mine ? 1 : 0);
        float v = mine ? val : 0.0f;
        #pragma unroll
        for (int o = 32; o; o >>= 1) v += __shfl_xor(v, o);
        if (lane == leader)
            atomicAdd(&base[(size_t)lkey * stride + off], v);
        active &= ~grp;
    }
}

// blocks [0,N): a[i] = x[i].w[0:128], c[i] = x[i].w[128:256]
// blocks [N,N+ZB): zero the ws region [mask | y | notsing] (4 KB/block)
__global__ void k_dots_zero(const float* __restrict__ x, const float* __restrict__ w,
                            float* __restrict__ a, float* __restrict__ c,
                            float4* __restrict__ zbase) {
    int b = blockIdx.x;
    int l = threadIdx.x;
    if (b < N) {
        const float* xi = x + b * FEAT;
        float pa = xi[l] * w[l] + xi[l + 64] * w[l + 64];
        float pc = xi[l] * w[FEAT + l] + xi[l + 64] * w[FEAT + l + 64];
        for (int off = 32; off; off >>= 1) {
            pa += __shfl_down(pa, off);
            pc += __shfl_down(pc, off);
        }
        if (l == 0) { a[b] = pa; c[b] = pc; }
    } else {
        size_t base = (size_t)(b - N) * 256;
        float4 z = {0.f, 0.f, 0.f, 0.f};
        zbase[base + l]       = z;
        zbase[base + 64 + l]  = z;
        zbase[base + 128 + l] = z;
        zbase[base + 192 + l] = z;
    }
}

// pack edges: u | v<<12 | fu<<24 | fv<<25, and mark not-single nodes
__global__ void k_edgeflags(const int* __restrict__ ei, const float* __restrict__ a,
                            const float* __restrict__ c, const float* __restrict__ bb,
                            unsigned* __restrict__ ep, int* __restrict__ notsingle) {
    int t = blockIdx.x * blockDim.x + threadIdx.x;
    if (t >= NE) return;
    int u = ei[t], v = ei[NE + t];
    unsigned wpk = (unsigned)u | ((unsigned)v << 12);
    if (u != v) {
        float b = bb[0];
        unsigned fu = (a[u] + c[v] + b > 0.f) ? 1u : 0u;
        unsigned fv = (a[v] + c[u] + b > 0.f) ? 1u : 0u;
        wpk |= (fu << 24) | (fv << 25);
        if (fu | fv) { notsingle[u] = 1; notsingle[v] = 1; }
    }
    ep[t] = wpk;
}

// single workgroup: LDS min-label propagation + pointer jumping to fixpoint,
// then root ranking (prefix sum) and cluster/out_cluster writes
__global__ void __launch_bounds__(1024)
k_prop_rank(const unsigned* __restrict__ ep, int* __restrict__ cluster,
            float* __restrict__ out_cluster) {
    __shared__ int lab[N];
    __shared__ int rk[N];
    __shared__ int ssum[1024];
    __shared__ int flag;
    int t = threadIdx.x;
    for (int i = t; i < N; i += 1024) lab[i] = i;
    for (;;) {
        __syncthreads();
        if (t == 0) flag = 0;
        __syncthreads();
        for (int e = t; e < NE; e += 1024) {
            unsigned wpk = ep[e];
            int u = wpk & 0xFFF, v = (wpk >> 12) & 0xFFF;
            if (wpk & (1u << 24)) {
                int lv = lab[v];
                if (lv < lab[u]) { atomicMin(&lab[u], lv); flag = 1; }
            }
            if (wpk & (1u << 25)) {
                int lu = lab[u];
                if (lu < lab[v]) { atomicMin(&lab[v], lu); flag = 1; }
            }
        }
        for (int i = t; i < N; i += 1024) {
            int m = lab[i];
            int mm = lab[m];
            while (mm < m) { m = mm; mm = lab[m]; }
            if (m < lab[i]) { atomicMin(&lab[i], m); flag = 1; }
        }
        __syncthreads();
        if (!flag) break;
    }
    // rank roots: cumsum(labels[i]==i) - 1; cluster[j] = rank[labels[j]]
    int i0 = 3 * t;
    int r0 = (lab[i0] == i0);
    int r1 = (lab[i0 + 1] == i0 + 1);
    int r2 = (lab[i0 + 2] == i0 + 2);
    int s = r0 + r1 + r2;
    ssum[t] = s;
    __syncthreads();
    for (int off = 1; off < 1024; off <<= 1) {
        int val = (t >= off) ? ssum[t - off] : 0;
        __syncthreads();
        ssum[t] += val;
        __syncthreads();
    }
    int run = ssum[t] - s;
    run += r0; rk[i0]     = run - 1;
    run += r1; rk[i0 + 1] = run - 1;
    run += r2; rk[i0 + 2] = run - 1;
    __syncthreads();
    for (int j = t; j < N; j += 1024) {
        int cl = rk[lab[j]];
        cluster[j] = cl;
        out_cluster[j] = (float)cl;
    }
}

// One lane per directed pair slot: dedup via bitmask, store ownership + score,
// wave-aggregated count into A_new[cluster[p]*N + cluster[q]].
__global__ void k_pairs(const unsigned* __restrict__ ep, const float* __restrict__ a,
                        const float* __restrict__ c, const float* __restrict__ bb,
                        const int* __restrict__ cluster, unsigned* __restrict__ mask,
                        unsigned char* __restrict__ own, float* __restrict__ ev,
                        float* __restrict__ Anew) {
    int t = blockIdx.x * blockDim.x + threadIdx.x;   // exactly NP threads
    int dir = (t >= NE) ? 1 : 0;
    int idx = dir ? t - NE : t;
    unsigned wpk = ep[idx];
    int u = wpk & 0xFFF, v = (wpk >> 12) & 0xFFF;
    int p = dir ? v : u;
    int q = dir ? u : v;
    int o = 0;
    if (u != v) {
        unsigned pos = (unsigned)p * N + (unsigned)q;
        unsigned bit = 1u << (pos & 31u);
        unsigned old = atomicOr(&mask[pos >> 5], bit);
        o = !(old & bit);
    }
    own[t] = (unsigned char)o;
    float e = 0.f;
    int key = 0;
    if (o) {
        e = tanhf(a[p] + c[q] + bb[0]);
        key = cluster[p] * N + cluster[q];
    }
    ev[t] = e;
    wave_agg_add(o != 0, key, 1.0f, Anew, 1, 0);
}

// waves [0,NP): y[q] += e(p,q)*x[p] for owned pairs (atomics spread over N rows)
// waves [NP,NP+N): isolated-under-contraction nodes: y[j] += x[j]
__global__ void k_scatter(const unsigned* __restrict__ ep, const float* __restrict__ x,
                          const unsigned char* __restrict__ own,
                          const float* __restrict__ ev,
                          const int* __restrict__ notsingle, float* __restrict__ y) {
    int wid = (blockIdx.x * blockDim.x + threadIdx.x) >> 6;
    int lane = threadIdx.x & 63;
    if (wid < NP) {
        if (!own[wid]) return;
        int dir = (wid >= NE) ? 1 : 0;
        int idx = dir ? wid - NE : wid;
        unsigned wpk = ep[idx];
        int u = wpk & 0xFFF, v = (wpk >> 12) & 0xFFF;
        int p = dir ? v : u;
        int q = dir ? u : v;
        float e = ev[wid];
        const float* xp = x + p * FEAT;
        float* yq = y + q * FEAT;
        atomicAdd(&yq[lane], e * xp[lane]);
        atomicAdd(&yq[lane + 64], e * xp[lane + 64]);
    } else {
        int j = wid - NP;
        if (notsingle[j]) return;
        const float* xp = x + j * FEAT;
        float* yq = y + j * FEAT;
        atomicAdd(&yq[lane], xp[lane]);
        atomicAdd(&yq[lane + 64], xp[lane + 64]);
    }
}

// waves [0,6144): X_new[cluster[q]][f] += y[q][f], wave-aggregated by cluster.
// waves [6144,6192): zero A_new diagonal.
__global__ void k_reduce(const float* __restrict__ y, const int* __restrict__ cluster,
                         float* __restrict__ Xnew, float* __restrict__ Anew) {
    int wid = (blockIdx.x * blockDim.x + threadIdx.x) >> 6;
    int lane = threadIdx.x & 63;
    if (wid < 6144) {
        int f = wid & (FEAT - 1);
        int chunk = wid >> 7;
        int q = chunk * 64 + lane;
        float val = y[q * FEAT + f];
        int key = cluster[q];
        wave_agg_add(true, key, val, Xnew, FEAT, f);
    } else {
        int i = (wid - 6144) * 64 + lane;
        Anew[(size_t)i * N + i] = 0.0f;
    }
}

extern "C" void kernel_launch(void* const* d_in, const int* in_sizes, int n_in,
                              void* d_out, int out_size, void* d_ws, size_t ws_size,
                              hipStream_t stream) {
    const float* x  = (const float*)d_in[0];
    const int*   ei = (const int*)d_in[1];
    const float* w  = (const float*)d_in[3];
    const float* bb = (const float*)d_in[4];

    // workspace layout — zeroed region [mask | y | notsing] FIRST (contiguous)
    char* ws = (char*)d_ws;
    size_t off = 0;
    unsigned* mask  = (unsigned*)(ws + off); off += (size_t)N * N / 8;        // 1,179,648
    float* y        = (float*)(ws + off);    off += (size_t)N * FEAT * 4;     // 1,572,864
    int* notsing    = (int*)(ws + off);      off += (size_t)N * 4;            //    12,288
    // (zero region total = 2,764,800 B = ZB * 4096)
    float* a        = (float*)(ws + off);    off += (size_t)N * 4;
    float* c        = (float*)(ws + off);    off += (size_t)N * 4;
    int* cluster    = (int*)(ws + off);      off += (size_t)N * 4;
    unsigned* ep    = (unsigned*)(ws + off); off += (size_t)NE * 4;
    unsigned char* own = (unsigned char*)(ws + off); off += NP;
    float* ev       = (float*)(ws + off);    off += (size_t)NP * 4;

    // output layout (all float32)
    float* Xnew        = (float*)d_out;                 // N*FEAT
    float* Anew        = Xnew + (size_t)N * FEAT;       // N*N
    float* out_cluster = Anew + (size_t)N * N + N;      // after new_batch (zeros)

    hipMemsetAsync(d_out, 0, (size_t)out_size * 4, stream);

    k_dots_zero<<<N + ZB, 64, 0, stream>>>(x, w, a, c, (float4*)ws);
    k_edgeflags<<<NE / 256, 256, 0, stream>>>(ei, a, c, bb, ep, notsing);
    k_prop_rank<<<1, 1024, 0, stream>>>(ep, cluster, out_cluster);
    k_pairs<<<NP / 256, 256, 0, stream>>>(ep, a, c, bb, cluster, mask, own, ev, Anew);
    k_scatter<<<((NP + N) * 64) / 256, 256, 0, stream>>>(ep, x, own, ev, notsing, y);
    k_reduce<<<(6192 * 64) / 256, 256, 0, stream>>>(y, cluster, Xnew, Anew);
}